// Round 2
// baseline (182.892 us; speedup 1.0000x reference)
//
#include <hip/hip_runtime.h>
#include <hip/hip_bf16.h>
#include <math.h>

#define DIN 512
#define DIM 512
#define NHEADS 8
#define DHEAD 64
#define NB 32
#define NPAD 512              // per-graph padded node slots
#define NPTOT (NB * NPAD)     // 16384

typedef __attribute__((ext_vector_type(8))) short bf16x8;
typedef __attribute__((ext_vector_type(8))) unsigned short u16x8;
typedef __attribute__((ext_vector_type(4))) float f32x4;

typedef __attribute__((address_space(3))) unsigned int lds_u32;
typedef __attribute__((address_space(1))) const unsigned int g_u32;

__device__ __forceinline__ void gll16(const unsigned short* g, unsigned short* l) {
  __builtin_amdgcn_global_load_lds((g_u32*)g, (lds_u32*)l, 16, 0, 0);
}

__device__ inline unsigned short f2bf(float x) {
  unsigned int u = __float_as_uint(x);
  unsigned int r = (u + 0x7FFFu + ((u >> 16) & 1u)) >> 16;
  return (unsigned short)r;
}

#define BAR()   __builtin_amdgcn_s_barrier()
#define LGKM0() asm volatile("s_waitcnt lgkmcnt(0)" ::: "memory")
#define LGKM8() asm volatile("s_waitcnt lgkmcnt(8)" ::: "memory")
#define VMCNT(n) asm volatile("s_waitcnt vmcnt(" #n ")" ::: "memory")

// ---------------- fused prep: LN rows | starts+map | 4 weight transposes ----------------
// grid.x = ntot/4 (LN) + ceil(ntot/256) (map) + 1024 (wtrans 16x16x4)
__global__ __launch_bounds__(256) void prep_kernel(const float* __restrict__ z,
                                                   const float* __restrict__ gamma,
                                                   const float* __restrict__ beta,
                                                   const int* __restrict__ src,
                                                   const float* __restrict__ Wq,
                                                   const float* __restrict__ Wk,
                                                   const float* __restrict__ Wv,
                                                   const float* __restrict__ Wo,
                                                   unsigned short* __restrict__ zn,
                                                   int* __restrict__ starts,
                                                   int* __restrict__ dstrow,
                                                   unsigned short* __restrict__ WtQKV,
                                                   unsigned short* __restrict__ WtO,
                                                   int ntot) {
  __shared__ float tile[32][33];
  int b = blockIdx.x;
  int nln = ntot >> 2;
  int nmap = (ntot + 255) >> 8;
  if (b < nln) {
    // ---- LayerNorm: one wave per row ----
    int wave = b * 4 + (threadIdx.x >> 6);
    int lane = threadIdx.x & 63;
    const float* row = z + (size_t)wave * DIN;
    float4 a = ((const float4*)row)[lane];
    float4 bb = ((const float4*)row)[64 + lane];
    float s  = a.x + a.y + a.z + a.w + bb.x + bb.y + bb.z + bb.w;
    float sq = a.x*a.x + a.y*a.y + a.z*a.z + a.w*a.w
             + bb.x*bb.x + bb.y*bb.y + bb.z*bb.z + bb.w*bb.w;
#pragma unroll
    for (int off = 32; off; off >>= 1) {
      s  += __shfl_xor(s, off);
      sq += __shfl_xor(sq, off);
    }
    float mu  = s * (1.0f / DIN);
    float var = sq * (1.0f / DIN) - mu * mu;
    float r   = rsqrtf(var + 1e-5f);
    float4 g0 = ((const float4*)gamma)[lane];
    float4 g1 = ((const float4*)gamma)[64 + lane];
    float4 b0 = ((const float4*)beta)[lane];
    float4 b1 = ((const float4*)beta)[64 + lane];
    ushort4 o0, o1;
    o0.x = f2bf((a.x - mu) * r * g0.x + b0.x);
    o0.y = f2bf((a.y - mu) * r * g0.y + b0.y);
    o0.z = f2bf((a.z - mu) * r * g0.z + b0.z);
    o0.w = f2bf((a.w - mu) * r * g0.w + b0.w);
    o1.x = f2bf((bb.x - mu) * r * g1.x + b1.x);
    o1.y = f2bf((bb.y - mu) * r * g1.y + b1.y);
    o1.z = f2bf((bb.z - mu) * r * g1.z + b1.z);
    o1.w = f2bf((bb.w - mu) * r * g1.w + b1.w);
    ((ushort4*)(zn + (size_t)wave * DIN))[lane] = o0;
    ((ushort4*)(zn + (size_t)wave * DIN))[64 + lane] = o1;
  } else if (b < nln + nmap) {
    // ---- starts (first block) + node -> padded-slot map ----
    int bid = b - nln;
    if (bid == 0 && threadIdx.x <= NB) {
      int gg = threadIdx.x;
      int lo = 0, hi = ntot;
      while (lo < hi) { int mid = (lo + hi) >> 1; if (src[mid] < gg) lo = mid + 1; else hi = mid; }
      starts[gg] = lo;
    }
    int i = bid * 256 + threadIdx.x;
    if (i < ntot) {
      int gg = src[i];
      int lo = 0, hi = ntot;
      while (lo < hi) { int mid = (lo + hi) >> 1; if (src[mid] < gg) lo = mid + 1; else hi = mid; }
      dstrow[i] = gg * NPAD + (i - lo);
    }
  } else {
    // ---- weight transpose + bf16 convert ----
    int idx = b - nln - nmap;              // 0..1023
    int zz = idx >> 8;                     // which weight
    int rem = idx & 255;
    const float* W; unsigned short* Wt;
    if (zz == 0)      { W = Wq; Wt = WtQKV; }
    else if (zz == 1) { W = Wk; Wt = WtQKV + (size_t)512 * DIN; }
    else if (zz == 2) { W = Wv; Wt = WtQKV + (size_t)1024 * DIN; }
    else              { W = Wo; Wt = WtO; }
    int k0 = (rem & 15) * 32;
    int n0 = (rem >> 4) * 32;
    int tx = threadIdx.x & 31;
    int ty = threadIdx.x >> 5;
#pragma unroll
    for (int i = 0; i < 4; i++)
      tile[ty + i * 8][tx] = W[(size_t)(k0 + ty + i * 8) * DIM + n0 + tx];
    __syncthreads();
#pragma unroll
    for (int i = 0; i < 4; i++)
      Wt[(size_t)(n0 + ty + i * 8) * DIN + k0 + tx] = f2bf(tile[tx][ty + i * 8]);
  }
}

// ---------------- 256x256 8-phase QKV GEMM (T2+T3+T4+T5), K=512 ----------------
// A [M][512] bf16, Bt [1536][512] bf16 (row = output col). C rows scattered via remap.
// 8 waves (2Mx4N); per wave 128x64 out as 2x2 quadrants of 64x32; 16 MFMA/phase.
// LDS: 2 K-tile parities x {A0,A1,B0,B1} half-tiles (128 rows x 64 k, 16KB) = 128KB.
// Staging: global_load_lds width 16, linear LDS dest, pre-swizzled global source
// (chunk p holds global k-chunk p^(row&7)); reads undo the same XOR -> conflict-free.
// Counted vmcnt(4) gates at phases 4/8 only; one vmcnt(0) drain on the last iter.
// r2: dynamic main loop (icache: ~7KB body vs ~26KB full-unroll); B-frags held in
// two register sets (bfE/bfO) loaded once per K-tile -> no P4/P8 LDS re-reads.
__global__ __launch_bounds__(512) void gemm_qkv_8ph(const unsigned short* __restrict__ A,
                                                    const unsigned short* __restrict__ Bt,
                                                    const int* __restrict__ remap,
                                                    unsigned short* __restrict__ C) {
  __shared__ unsigned short smem[65536];   // [par][A0,A1,B0,B1][8192] ; epilogue: C tile 256x256
  const int tid = threadIdx.x;
  const int lane = tid & 63, wv = tid >> 6;
  const int wr = wv >> 2, wc = wv & 3;          // 2 x 4 wave grid
  const int col16 = lane & 15, quad = lane >> 4;
  const int m0 = blockIdx.x * 256, n0 = blockIdx.y * 256;

  f32x4 acc[2][2][4][2];
#pragma unroll
  for (int qa = 0; qa < 2; ++qa)
#pragma unroll
    for (int qb = 0; qb < 2; ++qb)
#pragma unroll
      for (int mt = 0; mt < 4; ++mt)
#pragma unroll
        for (int nt = 0; nt < 2; ++nt) acc[qa][qb][mt][nt] = (f32x4){0.f, 0.f, 0.f, 0.f};

  bf16x8 af[4][2], bfE[2][2], bfO[2][2];

  // stage one half-tile (128 rows x 64 k): 16 chunks of 1KB, wave wv stages chunks wv*2, wv*2+1.
  // LDS chunk layout: lane l -> row c1k*8 + (l>>3), 16B slot (l&7); slot p holds global chunk p^(row&7).
  auto stage = [&](int par, int w, const unsigned short* G, int row0, int kt) {
    unsigned short* base = smem + par * 32768 + w * 8192;
#pragma unroll
    for (int i = 0; i < 2; ++i) {
      int c1k = wv * 2 + i;
      int r = row0 + c1k * 8 + (lane >> 3);
      int p = (lane & 7) ^ (lane >> 3);
      gll16(G + (size_t)r * 512 + kt * 64 + p * 8, base + c1k * 512);
    }
  };
  auto loadA = [&](int par, int half) {
    const unsigned short* base = smem + par * 32768 + half * 8192;
#pragma unroll
    for (int mt = 0; mt < 4; ++mt) {
      int r = wr * 64 + mt * 16 + col16;
      int sw = r & 7;
      af[mt][0] = *(const bf16x8*)&base[r * 64 + ((quad ^ sw) * 8)];
      af[mt][1] = *(const bf16x8*)&base[r * 64 + (((quad + 4) ^ sw) * 8)];
    }
  };
  auto loadB = [&](int par, int half, bf16x8 (&bb)[2][2]) {
    const unsigned short* base = smem + par * 32768 + (2 + half) * 8192;
#pragma unroll
    for (int nt = 0; nt < 2; ++nt) {
      int r = wc * 32 + nt * 16 + col16;
      int sw = r & 7;
      bb[nt][0] = *(const bf16x8*)&base[r * 64 + ((quad ^ sw) * 8)];
      bb[nt][1] = *(const bf16x8*)&base[r * 64 + (((quad + 4) ^ sw) * 8)];
    }
  };
  auto mfmaQ = [&](int qa, int qb, bf16x8 (&bb)[2][2]) {
    __builtin_amdgcn_s_setprio(1);
#pragma unroll
    for (int mt = 0; mt < 4; ++mt)
#pragma unroll
      for (int nt = 0; nt < 2; ++nt) {
        acc[qa][qb][mt][nt] =
            __builtin_amdgcn_mfma_f32_16x16x32_bf16(af[mt][0], bb[nt][0], acc[qa][qb][mt][nt], 0, 0, 0);
        acc[qa][qb][mt][nt] =
            __builtin_amdgcn_mfma_f32_16x16x32_bf16(af[mt][1], bb[nt][1], acc[qa][qb][mt][nt], 0, 0, 0);
      }
    __builtin_amdgcn_s_setprio(0);
  };

  // ---- prologue: tile0 {A0,B1,A1,B0} then tile1 {A0,B1}; gate leaves last 2 stages in flight ----
  stage(0, 0, A,  m0,       0);
  stage(0, 3, Bt, n0 + 128, 0);
  stage(0, 1, A,  m0 + 128, 0);
  stage(0, 2, Bt, n0,       0);
  stage(1, 0, A,  m0,       1);
  stage(1, 3, Bt, n0 + 128, 1);
  VMCNT(4);
  BAR();

  // ---- main loop: iter i computes K-tiles 2i (par0), 2i+1 (par1); stages 2i+1..2i+3 ----
  // quadrant order per K-tile: (00)(01)(11)(10) -> A-frags reused on phases 2,4,6,8;
  // B-frags (bfE=half0, bfO=half1) loaded once per K-tile, reused at P4/P8.
  // slot free->stage map: P1:Ao1<-A1(2i+1)  P2:Bo0<-B0(2i+1)  P3:Ae0<-A0(2i+2)  P4:Be1<-B1(2i+2)
  //                       P5:Ae1<-A1(2i+2)  P6:Be0<-B0(2i+2)  P7:Ao0<-A0(2i+3)  P8:Bo1<-B1(2i+3)
#pragma unroll 1
  for (int i = 0; i < 4; ++i) {
    const int t1 = 2 * i + 1, t2 = 2 * i + 2, t3 = 2 * i + 3;
    const bool more = (i < 3);
    // P1: reads Ae0,Be0
    loadA(0, 0); loadB(0, 0, bfE);
    stage(1, 1, A, m0 + 128, t1);
    LGKM8();
    BAR(); LGKM0();
    mfmaQ(0, 0, bfE);
    BAR();
    // P2: reads Be1 (A regs reused)
    loadB(0, 1, bfO);
    stage(1, 2, Bt, n0, t1);
    BAR(); LGKM0();
    mfmaQ(0, 1, bfO);
    BAR();
    // P3: reads Ae1 (B regs reused)
    loadA(0, 1);
    if (more) stage(0, 0, A, m0, t2);
    BAR(); LGKM0();
    mfmaQ(1, 1, bfO);
    BAR();
    // P4: no LDS reads (bfE reused)
    if (more) stage(0, 3, Bt, n0 + 128, t2);
    BAR(); LGKM0();
    mfmaQ(1, 0, bfE);
    if (more) { VMCNT(4); } else { VMCNT(0); }   // gate: Ao0,Bo0 landed before P5
    BAR();
    // P5: reads Ao0,Bo0
    loadA(1, 0); loadB(1, 0, bfE);
    if (more) stage(0, 1, A, m0 + 128, t2);
    LGKM8();
    BAR(); LGKM0();
    mfmaQ(0, 0, bfE);
    BAR();
    // P6: reads Bo1
    loadB(1, 1, bfO);
    if (more) stage(0, 2, Bt, n0, t2);
    BAR(); LGKM0();
    mfmaQ(0, 1, bfO);
    BAR();
    // P7: reads Ao1
    loadA(1, 1);
    if (more) stage(1, 0, A, m0, t3);
    BAR(); LGKM0();
    mfmaQ(1, 1, bfO);
    BAR();
    // P8: no LDS reads (bfE reused)
    if (more) stage(1, 3, Bt, n0 + 128, t3);
    BAR(); LGKM0();
    mfmaQ(1, 0, bfE);
    if (more) VMCNT(4);                          // gate: Ae0,Be0 landed before next P1
    BAR();
  }

  // ---- epilogue: acc -> LDS bf16 C tile (XOR-swizzled), then coalesced remapped 16B stores ----
#pragma unroll
  for (int qa = 0; qa < 2; ++qa)
#pragma unroll
    for (int qb = 0; qb < 2; ++qb)
#pragma unroll
      for (int mt = 0; mt < 4; ++mt)
#pragma unroll
        for (int nt = 0; nt < 2; ++nt)
#pragma unroll
          for (int r = 0; r < 4; ++r) {
            int row = qa * 128 + wr * 64 + mt * 16 + quad * 4 + r;
            int c   = qb * 128 + wc * 32 + nt * 16 + col16;
            smem[row * 256 + (((c >> 3) ^ (row & 31)) * 8) + (c & 7)] = f2bf(acc[qa][qb][mt][nt][r]);
          }
  __syncthreads();
#pragma unroll
  for (int pass = 0; pass < 16; ++pass) {
    int row = pass * 16 + (tid >> 5);
    int ch  = tid & 31;
    u16x8 v = *(const u16x8*)&smem[row * 256 + ((ch ^ (row & 31)) * 8)];
    int drow = remap[m0 + row];
    *(u16x8*)(C + (size_t)drow * 1536 + n0 + ch * 8) = v;
  }
}

// ---------------- m97-style staged GEMM (kept for the output projection) ----------------
template <int NCOLS, bool BIAS, bool OUT_F32, bool REMAP>
__global__ __launch_bounds__(256) void gemm_staged(const unsigned short* __restrict__ A,
                                                   const unsigned short* __restrict__ Bt,
                                                   const float* __restrict__ bias,
                                                   const int* __restrict__ remap,
                                                   unsigned short* __restrict__ Cbf,
                                                   float* __restrict__ Cf) {
  __shared__ unsigned short smem[16384];   // loop: A dbuf [0,8192) + B dbuf [8192,16384); epilogue: C tile
  int tid = threadIdx.x, lane = tid & 63, wv = tid >> 6;
  int col = lane & 15, quad = lane >> 4;
  int m0 = blockIdx.x * 128, n0 = blockIdx.y * 128;
  int msub = (wv & 1) * 64, nsub = (wv >> 1) * 64;

  int srow = lane >> 2;                                   // 0..15
  int cswz = (((lane & 3) ^ ((lane >> 3) & 3))) * 8;      // swizzled k-chunk (ushorts)

  f32x4 acc[4][4];
#pragma unroll
  for (int i = 0; i < 4; i++)
#pragma unroll
    for (int j = 0; j < 4; j++) acc[i][j] = (f32x4){0.f, 0.f, 0.f, 0.f};

  auto stage = [&](int ks, int nb) {
    const unsigned short* Ab = A  + (size_t)m0 * DIN + ks * 32;
    const unsigned short* Bb = Bt + (size_t)n0 * DIN + ks * 32;
#pragma unroll
    for (int i = 0; i < 2; i++) {
      int t = wv * 2 + i;  // 0..7 -> rows t*16..t*16+16
      gll16(Ab + (size_t)(t * 16 + srow) * DIN + cswz, smem + nb * 4096 + t * 512);
      gll16(Bb + (size_t)(t * 16 + srow) * DIN + cswz, smem + 8192 + nb * 4096 + t * 512);
    }
  };

  stage(0, 0);
#pragma unroll 2
  for (int ks = 0; ks < 16; ks++) {
    int cur = ks & 1;
    __syncthreads();
    if (ks + 1 < 16) stage(ks + 1, 1 - cur);
    bf16x8 af[4], bfr[4];
#pragma unroll
    for (int mt = 0; mt < 4; mt++) {
      int row = msub + mt * 16 + col;
      af[mt] = *(const bf16x8*)&smem[cur * 4096 + row * 32 + ((quad ^ ((row >> 1) & 3)) * 8)];
    }
#pragma unroll
    for (int nt = 0; nt < 4; nt++) {
      int row = nsub + nt * 16 + col;
      bfr[nt] = *(const bf16x8*)&smem[8192 + cur * 4096 + row * 32 + ((quad ^ ((row >> 1) & 3)) * 8)];
    }
#pragma unroll
    for (int mt = 0; mt < 4; mt++)
#pragma unroll
      for (int nt = 0; nt < 4; nt++)
        acc[mt][nt] = __builtin_amdgcn_mfma_f32_16x16x32_bf16(af[mt], bfr[nt], acc[mt][nt], 0, 0, 0);
  }

  if (!OUT_F32) {
    // ---- LDS-transposed epilogue: scalar swizzled LDS writes (2-way banks), coalesced 16B stores ----
    __syncthreads();
#pragma unroll
    for (int mt = 0; mt < 4; mt++)
#pragma unroll
      for (int r = 0; r < 4; r++) {
        int row = msub + mt * 16 + quad * 4 + r;   // (row>>2)&3 == quad
#pragma unroll
        for (int nt = 0; nt < 4; nt++) {
          int c = nsub + nt * 16 + col;
          float v = acc[mt][nt][r] + (BIAS ? bias[n0 + c] : 0.f);
          smem[row * 128 + (((c >> 3) ^ (quad << 1)) * 8) + (c & 7)] = f2bf(v);
        }
      }
    __syncthreads();
#pragma unroll
    for (int pass = 0; pass < 8; pass++) {
      int row = pass * 16 + (tid >> 4);
      int sw  = ((row >> 2) & 3) << 1;
      int ch  = tid & 15;
      u16x8 vv = *(const u16x8*)&smem[row * 128 + ((ch ^ sw) * 8)];
      int drow = REMAP ? remap[m0 + row] : (m0 + row);
      *(u16x8*)(Cbf + (size_t)drow * NCOLS + n0 + ch * 8) = vv;
    }
  } else {
#pragma unroll
    for (int mt = 0; mt < 4; mt++) {
#pragma unroll
      for (int r = 0; r < 4; r++) {
        int mrow = m0 + msub + mt * 16 + quad * 4 + r;
#pragma unroll
        for (int nt = 0; nt < 4; nt++) {
          int ncol = n0 + nsub + nt * 16 + col;
          Cf[(size_t)mrow * NCOLS + ncol] = acc[mt][nt][r] + (BIAS ? bias[ncol] : 0.f);
        }
      }
    }
  }
}

// ---------------- flash attention, no-max softmax, l via ones-MFMA ----------------
// block = 4 waves x 32 queries per (graph, head, 128-query tile); 64-key LDS dbuf tiles.
// K: b128 writes, key-row XOR swizzle. V: transposed in staging (scalar writes, swizzle
// chunk=(srow>>3)^((c>>4)<<1)^(c&7) -> 2 lanes/bank = free). No global V-transpose needed.
__global__ __launch_bounds__(256, 3) void fattn_kernel(const unsigned short* __restrict__ qkvp,
                                                       const int* __restrict__ starts,
                                                       unsigned short* __restrict__ obuf) {
  __shared__ unsigned short Kbuf[2][64 * 64];
  __shared__ unsigned short Vbuf[2][64 * 64];   // [dim][key], swizzled
  __shared__ unsigned short Plds[4][32 * 64];
  int g = blockIdx.x, h = blockIdx.y, qt = blockIdx.z;
  int st = starts[g];
  int n  = starts[g + 1] - st;
  int q0b = qt * 128;
  if (q0b >= n) return;  // uniform exit
  int tid = threadIdx.x, lane = tid & 63, wv = tid >> 6;
  int col = lane & 15, quad = lane >> 4;
  int q0 = q0b + wv * 32;
  bool active = q0 < n;
  int ntiles = (n + 63) >> 6;

  // Q fragments (A-layout); rows q0+a*16+col <= 511 always (pad reads are finite poison, discarded)
  bf16x8 qf[2][2];
  if (active) {
#pragma unroll
    for (int a = 0; a < 2; a++) {
      const unsigned short* qp = qkvp + (size_t)(g * NPAD + q0 + a * 16 + col) * 1536 + h * 64 + quad * 8;
      qf[a][0] = *(const bf16x8*)(qp);
      qf[a][1] = *(const bf16x8*)(qp + 32);
    }
  }

  // staging: thread -> K row srow, k-chunks sc,sc+1; V same row, dims c in [sc*8, sc*8+16)
  int srow = tid >> 2;          // 0..63
  int sc   = (tid & 3) * 2;     // 0,2,4,6
  int woff0 = srow * 64 + ((sc ^ (srow & 7)) * 8);
  int woff1 = srow * 64 + (((sc + 1) ^ (srow & 7)) * 8);
  u16x8 kreg0, kreg1, vreg0, vreg1;
  auto loadregs = [&](int kt) {
    const unsigned short* kp = qkvp + (size_t)(g * NPAD + kt + srow) * 1536 + 512 + h * 64 + sc * 8;
    kreg0 = *(const u16x8*)(kp);
    kreg1 = *(const u16x8*)(kp + 8);
    vreg0 = *(const u16x8*)(kp + 512);    // V lives +512 ushorts after K in the row
    vreg1 = *(const u16x8*)(kp + 520);
  };
  auto writelds = [&](int bsel) {
    *(u16x8*)&Kbuf[bsel][woff0] = kreg0;
    *(u16x8*)&Kbuf[bsel][woff1] = kreg1;
#pragma unroll
    for (int i = 0; i < 8; i++) {
      int c0 = sc * 8 + i;
      int c1 = sc * 8 + 8 + i;
      Vbuf[bsel][c0 * 64 + (((srow >> 3) ^ ((c0 >> 4) << 1) ^ (c0 & 7)) * 8) + (srow & 7)] = vreg0[i];
      Vbuf[bsel][c1 * 64 + (((srow >> 3) ^ ((c1 >> 4) << 1) ^ (c1 & 7)) * 8) + (srow & 7)] = vreg1[i];
    }
  };

  // all-ones B-fragment (bf16 1.0): D = P * ones^T gives row-sum l in every column
  bf16x8 onesv;
#pragma unroll
  for (int i = 0; i < 8; i++) onesv[i] = (short)0x3F80;

  f32x4 oa[2][4];
  f32x4 lacc[2];
#pragma unroll
  for (int a = 0; a < 2; a++) {
    lacc[a] = (f32x4){0.f, 0.f, 0.f, 0.f};
#pragma unroll
    for (int i = 0; i < 4; i++) oa[a][i] = (f32x4){0.f, 0.f, 0.f, 0.f};
  }

  loadregs(0);
  writelds(0);
  __syncthreads();

  for (int t = 0; t < ntiles; t++) {
    int cur = t & 1;
    if (t + 1 < ntiles) loadregs((t + 1) * 64);  // prefetch next tile into regs
    if (active) {
      // ---- S = Q K^T over 64 keys ----
      f32x4 s[2][4];
#pragma unroll
      for (int a = 0; a < 2; a++)
#pragma unroll
        for (int j = 0; j < 4; j++) s[a][j] = (f32x4){0.f, 0.f, 0.f, 0.f};
#pragma unroll
      for (int j = 0; j < 4; j++) {
        int R = j * 16 + col;
        bf16x8 kf0 = *(const bf16x8*)&Kbuf[cur][R * 64 + ((quad ^ (R & 7)) * 8)];
        bf16x8 kf1 = *(const bf16x8*)&Kbuf[cur][R * 64 + (((4 + quad) ^ (R & 7)) * 8)];
        s[0][j] = __builtin_amdgcn_mfma_f32_16x16x32_bf16(qf[0][0], kf0, s[0][j], 0, 0, 0);
        s[0][j] = __builtin_amdgcn_mfma_f32_16x16x32_bf16(qf[0][1], kf1, s[0][j], 0, 0, 0);
        s[1][j] = __builtin_amdgcn_mfma_f32_16x16x32_bf16(qf[1][0], kf0, s[1][j], 0, 0, 0);
        s[1][j] = __builtin_amdgcn_mfma_f32_16x16x32_bf16(qf[1][1], kf1, s[1][j], 0, 0, 0);
      }
      // ---- P = exp(S/8), masked; no max subtraction (|S/8| small, fp32 exp safe) ----
      int kt = t * 64;
#pragma unroll
      for (int j = 0; j < 4; j++) {
        bool valid = (kt + j * 16 + col) < n;
#pragma unroll
        for (int a = 0; a < 2; a++)
#pragma unroll
          for (int r = 0; r < 4; r++)
            s[a][j][r] = valid ? __expf(s[a][j][r] * 0.125f) : 0.f;
      }
      // ---- P: C-layout -> A-layout via per-wave LDS (swizzled scalar writes) ----
#pragma unroll
      for (int a = 0; a < 2; a++)
#pragma unroll
        for (int r = 0; r < 4; r++) {
          int R = a * 16 + quad * 4 + r;
#pragma unroll
          for (int j = 0; j < 4; j++) {
            int chunk = j * 2 + (col >> 3);
            Plds[wv][R * 64 + ((chunk ^ (R & 7)) * 8) + (col & 7)] = f2bf(s[a][j][r]);
          }
        }
      __builtin_amdgcn_fence(__ATOMIC_ACQ_REL, "workgroup");
      bf16x8 pf[2][2];
#pragma unroll
      for (int a = 0; a < 2; a++) {
        int R = a * 16 + col;
        pf[a][0] = *(const bf16x8*)&Plds[wv][R * 64 + ((quad ^ (col & 7)) * 8)];
        pf[a][1] = *(const bf16x8*)&Plds[wv][R * 64 + (((4 + quad) ^ (col & 7)) * 8)];
      }
      // ---- O += P V ; l += P * 1 ----
#pragma unroll
      for (int dt = 0; dt < 4; dt++) {
        int R = dt * 16 + col;
        int gR = ((R >> 4) << 1) ^ (R & 7);
        bf16x8 vf0 = *(const bf16x8*)&Vbuf[cur][R * 64 + ((quad ^ gR) * 8)];
        bf16x8 vf1 = *(const bf16x8*)&Vbuf[cur][R * 64 + (((quad + 4) ^ gR) * 8)];
        oa[0][dt] = __builtin_amdgcn_mfma_f32_16x16x32_bf16(pf[0][0], vf0, oa[0][dt], 0, 0, 0);
        oa[0][dt] = __builtin_amdgcn_mfma_f32_16x16x32_bf16(pf[0][1], vf1, oa[0][dt], 0, 0, 0);
        oa[1][dt] = __builtin_amdgcn_mfma_f32_16x16x32_bf16(pf[1][0], vf0, oa[1][dt], 0, 0, 0);
        oa[1][dt] = __builtin_amdgcn_mfma_f32_16x16x32_bf16(pf[1][1], vf1, oa[1][dt], 0, 0, 0);
      }
      lacc[0] = __builtin_amdgcn_mfma_f32_16x16x32_bf16(pf[0][0], onesv, lacc[0], 0, 0, 0);
      lacc[0] = __builtin_amdgcn_mfma_f32_16x16x32_bf16(pf[0][1], onesv, lacc[0], 0, 0, 0);
      lacc[1] = __builtin_amdgcn_mfma_f32_16x16x32_bf16(pf[1][0], onesv, lacc[1], 0, 0, 0);
      lacc[1] = __builtin_amdgcn_mfma_f32_16x16x32_bf16(pf[1][1], onesv, lacc[1], 0, 0, 0);
    }
    if (t + 1 < ntiles) writelds(1 - cur);
    __syncthreads();
  }

  if (active) {
#pragma unroll
    for (int a = 0; a < 2; a++)
#pragma unroll
      for (int r = 0; r < 4; r++) {
        int q = q0 + a * 16 + quad * 4 + r;
        if (q < n) {
          float inv = 1.0f / lacc[a][r];
          unsigned short* op = obuf + (size_t)(st + q) * DIM + h * 64 + col;
          op[0]  = f2bf(oa[a][0][r] * inv);
          op[16] = f2bf(oa[a][1][r] * inv);
          op[32] = f2bf(oa[a][2][r] * inv);
          op[48] = f2bf(oa[a][3][r] * inv);
        }
      }
  }
}

extern "C" void kernel_launch(void* const* d_in, const int* in_sizes, int n_in,
                              void* d_out, int out_size, void* d_ws, size_t ws_size,
                              hipStream_t stream) {
  const float* z     = (const float*)d_in[0];
  const int*   src   = (const int*)d_in[1];
  const float* gamma = (const float*)d_in[2];
  const float* beta  = (const float*)d_in[3];
  const float* Wq    = (const float*)d_in[4];
  const float* Wk    = (const float*)d_in[5];
  const float* Wv    = (const float*)d_in[6];
  const float* Wo    = (const float*)d_in[7];
  const float* bo    = (const float*)d_in[8];
  int ntot = in_sizes[0] / DIN;
  float* out = (float*)d_out;

  char* ws = (char*)d_ws;
  size_t off = 0;
  unsigned short* zn    = (unsigned short*)(ws + off); off += (size_t)ntot * DIN * 2;
  unsigned short* qkvp  = (unsigned short*)(ws + off); off += (size_t)NPTOT * 1536 * 2;
  unsigned short* obuf  = (unsigned short*)(ws + off); off += (size_t)ntot * DIM * 2;
  unsigned short* WtQKV = (unsigned short*)(ws + off); off += (size_t)1536 * DIN * 2;
  unsigned short* WtO   = (unsigned short*)(ws + off); off += (size_t)DIM * DIN * 2;
  int* starts           = (int*)(ws + off);            off += 64 * 4;
  int* dstrow           = (int*)(ws + off);

  int nln = ntot >> 2;
  int nmap = (ntot + 255) >> 8;
  prep_kernel<<<nln + nmap + 1024, 256, 0, stream>>>(z, gamma, beta, src, Wq, Wk, Wv, Wo,
                                                     zn, starts, dstrow, WtQKV, WtO, ntot);

  // qkvp[g*512+pos][0..1536) = zn @ [Wq|Wk|Wv] (rows scattered to padded slots)
  // 256x256 8-phase pipeline: grid 48x6 = 288 blocks, 512 threads, 128KB LDS (1 block/CU)
  gemm_qkv_8ph<<<dim3(ntot / 256, 1536 / 256), 512, 0, stream>>>(zn, WtQKV, dstrow, qkvp);

  // flash attention: grid (graphs, heads, 128-query tiles); V transposed in-LDS
  fattn_kernel<<<dim3(NB, NHEADS, 4), 256, 0, stream>>>(qkvp, starts, obuf);

  // out = obuf @ Wo + bo -> fp32
  gemm_staged<512, true, true, false>
      <<<dim3(ntot / 128, 4), 256, 0, stream>>>(obuf, WtO, bo, nullptr, nullptr, out);
}

// Round 3
// 175.830 us; speedup vs baseline: 1.0402x; 1.0402x over previous
//
#include <hip/hip_runtime.h>
#include <hip/hip_bf16.h>
#include <math.h>

#define DIN 512
#define DIM 512
#define NHEADS 8
#define DHEAD 64
#define NB 32
#define NPAD 512              // per-graph padded node slots
#define NPTOT (NB * NPAD)     // 16384

typedef __attribute__((ext_vector_type(8))) short bf16x8;
typedef __attribute__((ext_vector_type(8))) unsigned short u16x8;
typedef __attribute__((ext_vector_type(4))) float f32x4;

typedef __attribute__((address_space(3))) unsigned int lds_u32;
typedef __attribute__((address_space(1))) const unsigned int g_u32;

__device__ __forceinline__ void gll16(const unsigned short* g, unsigned short* l) {
  __builtin_amdgcn_global_load_lds((g_u32*)g, (lds_u32*)l, 16, 0, 0);
}

__device__ inline unsigned short f2bf(float x) {
  unsigned int u = __float_as_uint(x);
  unsigned int r = (u + 0x7FFFu + ((u >> 16) & 1u)) >> 16;
  return (unsigned short)r;
}

#define BAR()   __builtin_amdgcn_s_barrier()
#define LGKM0() asm volatile("s_waitcnt lgkmcnt(0)" ::: "memory")
#define LGKM8() asm volatile("s_waitcnt lgkmcnt(8)" ::: "memory")
#define VMCNT(n) asm volatile("s_waitcnt vmcnt(" #n ")" ::: "memory")

// ---------------- fused prep: LN rows | starts+map | 4 weight transposes ----------------
// grid.x = ntot/4 (LN) + ceil(ntot/256) (map) + 1024 (wtrans 16x16x4)
__global__ __launch_bounds__(256) void prep_kernel(const float* __restrict__ z,
                                                   const float* __restrict__ gamma,
                                                   const float* __restrict__ beta,
                                                   const int* __restrict__ src,
                                                   const float* __restrict__ Wq,
                                                   const float* __restrict__ Wk,
                                                   const float* __restrict__ Wv,
                                                   const float* __restrict__ Wo,
                                                   unsigned short* __restrict__ zn,
                                                   int* __restrict__ starts,
                                                   int* __restrict__ dstrow,
                                                   unsigned short* __restrict__ WtQKV,
                                                   unsigned short* __restrict__ WtO,
                                                   int ntot) {
  __shared__ float tile[32][33];
  int b = blockIdx.x;
  int nln = ntot >> 2;
  int nmap = (ntot + 255) >> 8;
  if (b < nln) {
    // ---- LayerNorm: one wave per row ----
    int wave = b * 4 + (threadIdx.x >> 6);
    int lane = threadIdx.x & 63;
    const float* row = z + (size_t)wave * DIN;
    float4 a = ((const float4*)row)[lane];
    float4 bb = ((const float4*)row)[64 + lane];
    float s  = a.x + a.y + a.z + a.w + bb.x + bb.y + bb.z + bb.w;
    float sq = a.x*a.x + a.y*a.y + a.z*a.z + a.w*a.w
             + bb.x*bb.x + bb.y*bb.y + bb.z*bb.z + bb.w*bb.w;
#pragma unroll
    for (int off = 32; off; off >>= 1) {
      s  += __shfl_xor(s, off);
      sq += __shfl_xor(sq, off);
    }
    float mu  = s * (1.0f / DIN);
    float var = sq * (1.0f / DIN) - mu * mu;
    float r   = rsqrtf(var + 1e-5f);
    float4 g0 = ((const float4*)gamma)[lane];
    float4 g1 = ((const float4*)gamma)[64 + lane];
    float4 b0 = ((const float4*)beta)[lane];
    float4 b1 = ((const float4*)beta)[64 + lane];
    ushort4 o0, o1;
    o0.x = f2bf((a.x - mu) * r * g0.x + b0.x);
    o0.y = f2bf((a.y - mu) * r * g0.y + b0.y);
    o0.z = f2bf((a.z - mu) * r * g0.z + b0.z);
    o0.w = f2bf((a.w - mu) * r * g0.w + b0.w);
    o1.x = f2bf((bb.x - mu) * r * g1.x + b1.x);
    o1.y = f2bf((bb.y - mu) * r * g1.y + b1.y);
    o1.z = f2bf((bb.z - mu) * r * g1.z + b1.z);
    o1.w = f2bf((bb.w - mu) * r * g1.w + b1.w);
    ((ushort4*)(zn + (size_t)wave * DIN))[lane] = o0;
    ((ushort4*)(zn + (size_t)wave * DIN))[64 + lane] = o1;
  } else if (b < nln + nmap) {
    // ---- starts (first block) + node -> padded-slot map ----
    int bid = b - nln;
    if (bid == 0 && threadIdx.x <= NB) {
      int gg = threadIdx.x;
      int lo = 0, hi = ntot;
      while (lo < hi) { int mid = (lo + hi) >> 1; if (src[mid] < gg) lo = mid + 1; else hi = mid; }
      starts[gg] = lo;
    }
    int i = bid * 256 + threadIdx.x;
    if (i < ntot) {
      int gg = src[i];
      int lo = 0, hi = ntot;
      while (lo < hi) { int mid = (lo + hi) >> 1; if (src[mid] < gg) lo = mid + 1; else hi = mid; }
      dstrow[i] = gg * NPAD + (i - lo);
    }
  } else {
    // ---- weight transpose + bf16 convert ----
    int idx = b - nln - nmap;              // 0..1023
    int zz = idx >> 8;                     // which weight
    int rem = idx & 255;
    const float* W; unsigned short* Wt;
    if (zz == 0)      { W = Wq; Wt = WtQKV; }
    else if (zz == 1) { W = Wk; Wt = WtQKV + (size_t)512 * DIN; }
    else if (zz == 2) { W = Wv; Wt = WtQKV + (size_t)1024 * DIN; }
    else              { W = Wo; Wt = WtO; }
    int k0 = (rem & 15) * 32;
    int n0 = (rem >> 4) * 32;
    int tx = threadIdx.x & 31;
    int ty = threadIdx.x >> 5;
#pragma unroll
    for (int i = 0; i < 4; i++)
      tile[ty + i * 8][tx] = W[(size_t)(k0 + ty + i * 8) * DIM + n0 + tx];
    __syncthreads();
#pragma unroll
    for (int i = 0; i < 4; i++)
      Wt[(size_t)(n0 + ty + i * 8) * DIN + k0 + tx] = f2bf(tile[tx][ty + i * 8]);
  }
}

// ---------------- 8-phase QKV GEMM body (T2+T3+T4+T5), K=512, BN=256 ----------------
// Templated on MT = m-frags per half-tile per wave: MT=4 -> BM=256, MT=2 -> BM=128.
// 8 waves (2Mx4N); quadrant order (00)(01)(11)(10); B-frags held in bfE/bfO register sets.
// LDS: 2 K-tile parities x {A0,A1,B0,B1} slots of 16KB = 128KB (half variant underfills A slots).
// Staging: global_load_lds width 16, linear LDS dest, pre-swizzled global source.
// Half variant: waves 4-7 duplicate-stage A chunks (same data, same dest -> benign) so EVERY
// stage() issues exactly 2 gll16/thread in both variants -> vmcnt ledger identical.
template <int MT>
__device__ __forceinline__ void qkv_body(const unsigned short* __restrict__ A,
                                         const unsigned short* __restrict__ Bt,
                                         const int* __restrict__ remap,
                                         unsigned short* __restrict__ C,
                                         unsigned short* smem, int m0, int n0) {
  constexpr int BM = MT * 64;   // 256 or 128
  constexpr int HM = MT * 32;   // rows per half-tile: 128 or 64
  const int tid = threadIdx.x;
  const int lane = tid & 63, wv = tid >> 6;
  const int wr = wv >> 2, wc = wv & 3;          // 2 x 4 wave grid
  const int col16 = lane & 15, quad = lane >> 4;

  f32x4 acc[2][2][MT][2];
#pragma unroll
  for (int qa = 0; qa < 2; ++qa)
#pragma unroll
    for (int qb = 0; qb < 2; ++qb)
#pragma unroll
      for (int mt = 0; mt < MT; ++mt)
#pragma unroll
        for (int nt = 0; nt < 2; ++nt) acc[qa][qb][mt][nt] = (f32x4){0.f, 0.f, 0.f, 0.f};

  bf16x8 af[MT][2], bfE[2][2], bfO[2][2];

  // stage one half-tile: chunks of 1KB; lane l -> row c1k*8 + (l>>3), swizzled 16B slot.
  auto stage = [&](int par, int w, const unsigned short* G, int row0, int kt, bool isA) {
    unsigned short* base = smem + par * 32768 + w * 8192;
#pragma unroll
    for (int i = 0; i < 2; ++i) {
      int c1k = (isA && MT == 2) ? ((wv & 3) * 2 + i)   // 8 chunks, waves 4-7 duplicate
                                 : (wv * 2 + i);        // 16 chunks
      int r = row0 + c1k * 8 + (lane >> 3);
      int p = (lane & 7) ^ (lane >> 3);
      gll16(G + (size_t)r * 512 + kt * 64 + p * 8, base + c1k * 512);
    }
  };
  auto loadA = [&](int par, int half) {
    const unsigned short* base = smem + par * 32768 + half * 8192;
#pragma unroll
    for (int mt = 0; mt < MT; ++mt) {
      int r = wr * (HM / 2) + mt * 16 + col16;
      int sw = r & 7;
      af[mt][0] = *(const bf16x8*)&base[r * 64 + ((quad ^ sw) * 8)];
      af[mt][1] = *(const bf16x8*)&base[r * 64 + (((quad + 4) ^ sw) * 8)];
    }
  };
  auto loadB = [&](int par, int half, bf16x8 (&bb)[2][2]) {
    const unsigned short* base = smem + par * 32768 + (2 + half) * 8192;
#pragma unroll
    for (int nt = 0; nt < 2; ++nt) {
      int r = wc * 32 + nt * 16 + col16;
      int sw = r & 7;
      bb[nt][0] = *(const bf16x8*)&base[r * 64 + ((quad ^ sw) * 8)];
      bb[nt][1] = *(const bf16x8*)&base[r * 64 + (((quad + 4) ^ sw) * 8)];
    }
  };
  auto mfmaQ = [&](int qa, int qb, bf16x8 (&bb)[2][2]) {
    __builtin_amdgcn_s_setprio(1);
#pragma unroll
    for (int mt = 0; mt < MT; ++mt)
#pragma unroll
      for (int nt = 0; nt < 2; ++nt) {
        acc[qa][qb][mt][nt] =
            __builtin_amdgcn_mfma_f32_16x16x32_bf16(af[mt][0], bb[nt][0], acc[qa][qb][mt][nt], 0, 0, 0);
        acc[qa][qb][mt][nt] =
            __builtin_amdgcn_mfma_f32_16x16x32_bf16(af[mt][1], bb[nt][1], acc[qa][qb][mt][nt], 0, 0, 0);
      }
    __builtin_amdgcn_s_setprio(0);
  };

  // ---- prologue: tile0 {A0,B1,A1,B0} then tile1 {A0,B1}; gate leaves last 2 stages in flight ----
  stage(0, 0, A,  m0,       0, true);
  stage(0, 3, Bt, n0 + 128, 0, false);
  stage(0, 1, A,  m0 + HM,  0, true);
  stage(0, 2, Bt, n0,       0, false);
  stage(1, 0, A,  m0,       1, true);
  stage(1, 3, Bt, n0 + 128, 1, false);
  VMCNT(4);
  BAR();

  // ---- main loop: iter i computes K-tiles 2i (par0), 2i+1 (par1); stages 2i+1..2i+3 ----
  // slot free->stage map: P1:Ao1<-A1(2i+1)  P2:Bo0<-B0(2i+1)  P3:Ae0<-A0(2i+2)  P4:Be1<-B1(2i+2)
  //                       P5:Ae1<-A1(2i+2)  P6:Be0<-B0(2i+2)  P7:Ao0<-A0(2i+3)  P8:Bo1<-B1(2i+3)
#pragma unroll 1
  for (int i = 0; i < 4; ++i) {
    const int t1 = 2 * i + 1, t2 = 2 * i + 2, t3 = 2 * i + 3;
    const bool more = (i < 3);
    // P1: reads Ae0,Be0
    loadA(0, 0); loadB(0, 0, bfE);
    stage(1, 1, A, m0 + HM, t1, true);
    LGKM8();
    BAR(); LGKM0();
    mfmaQ(0, 0, bfE);
    BAR();
    // P2: reads Be1 (A regs reused)
    loadB(0, 1, bfO);
    stage(1, 2, Bt, n0, t1, false);
    BAR(); LGKM0();
    mfmaQ(0, 1, bfO);
    BAR();
    // P3: reads Ae1 (B regs reused)
    loadA(0, 1);
    if (more) stage(0, 0, A, m0, t2, true);
    BAR(); LGKM0();
    mfmaQ(1, 1, bfO);
    BAR();
    // P4: no LDS reads (bfE reused)
    if (more) stage(0, 3, Bt, n0 + 128, t2, false);
    BAR(); LGKM0();
    mfmaQ(1, 0, bfE);
    if (more) { VMCNT(4); } else { VMCNT(0); }   // gate: Ao0,Bo0 landed before P5
    BAR();
    // P5: reads Ao0,Bo0
    loadA(1, 0); loadB(1, 0, bfE);
    if (more) stage(0, 1, A, m0 + HM, t2, true);
    LGKM8();
    BAR(); LGKM0();
    mfmaQ(0, 0, bfE);
    BAR();
    // P6: reads Bo1
    loadB(1, 1, bfO);
    if (more) stage(0, 2, Bt, n0, t2, false);
    BAR(); LGKM0();
    mfmaQ(0, 1, bfO);
    BAR();
    // P7: reads Ao1
    loadA(1, 1);
    if (more) stage(1, 0, A, m0, t3, true);
    BAR(); LGKM0();
    mfmaQ(1, 1, bfO);
    BAR();
    // P8: no LDS reads (bfE reused)
    if (more) stage(1, 3, Bt, n0 + 128, t3, false);
    BAR(); LGKM0();
    mfmaQ(1, 0, bfE);
    if (more) VMCNT(4);                          // gate: Ae0,Be0 landed before next P1
    BAR();
  }

  // ---- epilogue: acc -> LDS bf16 C tile (XOR-swizzled), then coalesced remapped 16B stores ----
#pragma unroll
  for (int qa = 0; qa < 2; ++qa)
#pragma unroll
    for (int qb = 0; qb < 2; ++qb)
#pragma unroll
      for (int mt = 0; mt < MT; ++mt)
#pragma unroll
        for (int nt = 0; nt < 2; ++nt)
#pragma unroll
          for (int r = 0; r < 4; ++r) {
            int row = qa * HM + wr * (HM / 2) + mt * 16 + quad * 4 + r;
            int c   = qb * 128 + wc * 32 + nt * 16 + col16;
            smem[row * 256 + (((c >> 3) ^ (row & 31)) * 8) + (c & 7)] = f2bf(acc[qa][qb][mt][nt][r]);
          }
  __syncthreads();
#pragma unroll
  for (int pass = 0; pass < BM / 16; ++pass) {
    int row = pass * 16 + (tid >> 5);
    int ch  = tid & 31;
    u16x8 v = *(const u16x8*)&smem[row * 256 + ((ch ^ (row & 31)) * 8)];
    int drow = remap[m0 + row];
    *(u16x8*)(C + (size_t)drow * 1536 + n0 + ch * 8) = v;
  }
}

// hybrid grid: jobs [0, mbig*6) are 256x256 tiles; jobs [mbig*6, mbig*6+72) are 128x256
// tail tiles covering the last 1536 rows. Bigs dispatch first -> tail round is half-length.
__global__ __launch_bounds__(512) void gemm_qkv_8ph(const unsigned short* __restrict__ A,
                                                    const unsigned short* __restrict__ Bt,
                                                    const int* __restrict__ remap,
                                                    unsigned short* __restrict__ C,
                                                    int mbig) {
  __shared__ unsigned short smem[65536];
  int j = blockIdx.x;
  int nbigj = mbig * 6;
  if (j < nbigj) {
    qkv_body<4>(A, Bt, remap, C, smem, (j / 6) * 256, (j % 6) * 256);
  } else {
    int q = j - nbigj;
    qkv_body<2>(A, Bt, remap, C, smem, mbig * 256 + (q / 6) * 128, (q % 6) * 256);
  }
}

// ---------------- m97-style staged GEMM (kept for the output projection) ----------------
template <int NCOLS, bool BIAS, bool OUT_F32, bool REMAP>
__global__ __launch_bounds__(256) void gemm_staged(const unsigned short* __restrict__ A,
                                                   const unsigned short* __restrict__ Bt,
                                                   const float* __restrict__ bias,
                                                   const int* __restrict__ remap,
                                                   unsigned short* __restrict__ Cbf,
                                                   float* __restrict__ Cf) {
  __shared__ unsigned short smem[16384];   // loop: A dbuf [0,8192) + B dbuf [8192,16384); epilogue: C tile
  int tid = threadIdx.x, lane = tid & 63, wv = tid >> 6;
  int col = lane & 15, quad = lane >> 4;
  int m0 = blockIdx.x * 128, n0 = blockIdx.y * 128;
  int msub = (wv & 1) * 64, nsub = (wv >> 1) * 64;

  int srow = lane >> 2;                                   // 0..15
  int cswz = (((lane & 3) ^ ((lane >> 3) & 3))) * 8;      // swizzled k-chunk (ushorts)

  f32x4 acc[4][4];
#pragma unroll
  for (int i = 0; i < 4; i++)
#pragma unroll
    for (int j = 0; j < 4; j++) acc[i][j] = (f32x4){0.f, 0.f, 0.f, 0.f};

  auto stage = [&](int ks, int nb) {
    const unsigned short* Ab = A  + (size_t)m0 * DIN + ks * 32;
    const unsigned short* Bb = Bt + (size_t)n0 * DIN + ks * 32;
#pragma unroll
    for (int i = 0; i < 2; i++) {
      int t = wv * 2 + i;  // 0..7 -> rows t*16..t*16+16
      gll16(Ab + (size_t)(t * 16 + srow) * DIN + cswz, smem + nb * 4096 + t * 512);
      gll16(Bb + (size_t)(t * 16 + srow) * DIN + cswz, smem + 8192 + nb * 4096 + t * 512);
    }
  };

  stage(0, 0);
#pragma unroll 2
  for (int ks = 0; ks < 16; ks++) {
    int cur = ks & 1;
    __syncthreads();
    if (ks + 1 < 16) stage(ks + 1, 1 - cur);
    bf16x8 af[4], bfr[4];
#pragma unroll
    for (int mt = 0; mt < 4; mt++) {
      int row = msub + mt * 16 + col;
      af[mt] = *(const bf16x8*)&smem[cur * 4096 + row * 32 + ((quad ^ ((row >> 1) & 3)) * 8)];
    }
#pragma unroll
    for (int nt = 0; nt < 4; nt++) {
      int row = nsub + nt * 16 + col;
      bfr[nt] = *(const bf16x8*)&smem[8192 + cur * 4096 + row * 32 + ((quad ^ ((row >> 1) & 3)) * 8)];
    }
#pragma unroll
    for (int mt = 0; mt < 4; mt++)
#pragma unroll
      for (int nt = 0; nt < 4; nt++)
        acc[mt][nt] = __builtin_amdgcn_mfma_f32_16x16x32_bf16(af[mt], bfr[nt], acc[mt][nt], 0, 0, 0);
  }

  if (!OUT_F32) {
    // ---- LDS-transposed epilogue: scalar swizzled LDS writes (2-way banks), coalesced 16B stores ----
    __syncthreads();
#pragma unroll
    for (int mt = 0; mt < 4; mt++)
#pragma unroll
      for (int r = 0; r < 4; r++) {
        int row = msub + mt * 16 + quad * 4 + r;   // (row>>2)&3 == quad
#pragma unroll
        for (int nt = 0; nt < 4; nt++) {
          int c = nsub + nt * 16 + col;
          float v = acc[mt][nt][r] + (BIAS ? bias[n0 + c] : 0.f);
          smem[row * 128 + (((c >> 3) ^ (quad << 1)) * 8) + (c & 7)] = f2bf(v);
        }
      }
    __syncthreads();
#pragma unroll
    for (int pass = 0; pass < 8; pass++) {
      int row = pass * 16 + (tid >> 4);
      int sw  = ((row >> 2) & 3) << 1;
      int ch  = tid & 15;
      u16x8 vv = *(const u16x8*)&smem[row * 128 + ((ch ^ sw) * 8)];
      int drow = REMAP ? remap[m0 + row] : (m0 + row);
      *(u16x8*)(Cbf + (size_t)drow * NCOLS + n0 + ch * 8) = vv;
    }
  } else {
#pragma unroll
    for (int mt = 0; mt < 4; mt++) {
#pragma unroll
      for (int r = 0; r < 4; r++) {
        int mrow = m0 + msub + mt * 16 + quad * 4 + r;
#pragma unroll
        for (int nt = 0; nt < 4; nt++) {
          int ncol = n0 + nsub + nt * 16 + col;
          Cf[(size_t)mrow * NCOLS + ncol] = acc[mt][nt][r] + (BIAS ? bias[ncol] : 0.f);
        }
      }
    }
  }
}

// ---------------- flash attention, no-max softmax, l via ones-MFMA ----------------
// block = 4 waves x 32 queries per (graph, head, 128-query tile); 64-key LDS dbuf tiles.
// K: b128 writes, key-row XOR swizzle. V: transposed in staging (scalar writes, swizzle
// chunk=(srow>>3)^((c>>4)<<1)^(c&7) -> 2 lanes/bank = free). No global V-transpose needed.
__global__ __launch_bounds__(256, 3) void fattn_kernel(const unsigned short* __restrict__ qkvp,
                                                       const int* __restrict__ starts,
                                                       unsigned short* __restrict__ obuf) {
  __shared__ unsigned short Kbuf[2][64 * 64];
  __shared__ unsigned short Vbuf[2][64 * 64];   // [dim][key], swizzled
  __shared__ unsigned short Plds[4][32 * 64];
  int g = blockIdx.x, h = blockIdx.y, qt = blockIdx.z;
  int st = starts[g];
  int n  = starts[g + 1] - st;
  int q0b = qt * 128;
  if (q0b >= n) return;  // uniform exit
  int tid = threadIdx.x, lane = tid & 63, wv = tid >> 6;
  int col = lane & 15, quad = lane >> 4;
  int q0 = q0b + wv * 32;
  bool active = q0 < n;
  int ntiles = (n + 63) >> 6;

  // Q fragments (A-layout); rows q0+a*16+col <= 511 always (pad reads are finite poison, discarded)
  bf16x8 qf[2][2];
  if (active) {
#pragma unroll
    for (int a = 0; a < 2; a++) {
      const unsigned short* qp = qkvp + (size_t)(g * NPAD + q0 + a * 16 + col) * 1536 + h * 64 + quad * 8;
      qf[a][0] = *(const bf16x8*)(qp);
      qf[a][1] = *(const bf16x8*)(qp + 32);
    }
  }

  // staging: thread -> K row srow, k-chunks sc,sc+1; V same row, dims c in [sc*8, sc*8+16)
  int srow = tid >> 2;          // 0..63
  int sc   = (tid & 3) * 2;     // 0,2,4,6
  int woff0 = srow * 64 + ((sc ^ (srow & 7)) * 8);
  int woff1 = srow * 64 + (((sc + 1) ^ (srow & 7)) * 8);
  u16x8 kreg0, kreg1, vreg0, vreg1;
  auto loadregs = [&](int kt) {
    const unsigned short* kp = qkvp + (size_t)(g * NPAD + kt + srow) * 1536 + 512 + h * 64 + sc * 8;
    kreg0 = *(const u16x8*)(kp);
    kreg1 = *(const u16x8*)(kp + 8);
    vreg0 = *(const u16x8*)(kp + 512);    // V lives +512 ushorts after K in the row
    vreg1 = *(const u16x8*)(kp + 520);
  };
  auto writelds = [&](int bsel) {
    *(u16x8*)&Kbuf[bsel][woff0] = kreg0;
    *(u16x8*)&Kbuf[bsel][woff1] = kreg1;
#pragma unroll
    for (int i = 0; i < 8; i++) {
      int c0 = sc * 8 + i;
      int c1 = sc * 8 + 8 + i;
      Vbuf[bsel][c0 * 64 + (((srow >> 3) ^ ((c0 >> 4) << 1) ^ (c0 & 7)) * 8) + (srow & 7)] = vreg0[i];
      Vbuf[bsel][c1 * 64 + (((srow >> 3) ^ ((c1 >> 4) << 1) ^ (c1 & 7)) * 8) + (srow & 7)] = vreg1[i];
    }
  };

  // all-ones B-fragment (bf16 1.0): D = P * ones^T gives row-sum l in every column
  bf16x8 onesv;
#pragma unroll
  for (int i = 0; i < 8; i++) onesv[i] = (short)0x3F80;

  f32x4 oa[2][4];
  f32x4 lacc[2];
#pragma unroll
  for (int a = 0; a < 2; a++) {
    lacc[a] = (f32x4){0.f, 0.f, 0.f, 0.f};
#pragma unroll
    for (int i = 0; i < 4; i++) oa[a][i] = (f32x4){0.f, 0.f, 0.f, 0.f};
  }

  loadregs(0);
  writelds(0);
  __syncthreads();

  for (int t = 0; t < ntiles; t++) {
    int cur = t & 1;
    if (t + 1 < ntiles) loadregs((t + 1) * 64);  // prefetch next tile into regs
    if (active) {
      // ---- S = Q K^T over 64 keys ----
      f32x4 s[2][4];
#pragma unroll
      for (int a = 0; a < 2; a++)
#pragma unroll
        for (int j = 0; j < 4; j++) s[a][j] = (f32x4){0.f, 0.f, 0.f, 0.f};
#pragma unroll
      for (int j = 0; j < 4; j++) {
        int R = j * 16 + col;
        bf16x8 kf0 = *(const bf16x8*)&Kbuf[cur][R * 64 + ((quad ^ (R & 7)) * 8)];
        bf16x8 kf1 = *(const bf16x8*)&Kbuf[cur][R * 64 + (((4 + quad) ^ (R & 7)) * 8)];
        s[0][j] = __builtin_amdgcn_mfma_f32_16x16x32_bf16(qf[0][0], kf0, s[0][j], 0, 0, 0);
        s[0][j] = __builtin_amdgcn_mfma_f32_16x16x32_bf16(qf[0][1], kf1, s[0][j], 0, 0, 0);
        s[1][j] = __builtin_amdgcn_mfma_f32_16x16x32_bf16(qf[1][0], kf0, s[1][j], 0, 0, 0);
        s[1][j] = __builtin_amdgcn_mfma_f32_16x16x32_bf16(qf[1][1], kf1, s[1][j], 0, 0, 0);
      }
      // ---- P = exp(S/8), masked; no max subtraction (|S/8| small, fp32 exp safe) ----
      int kt = t * 64;
#pragma unroll
      for (int j = 0; j < 4; j++) {
        bool valid = (kt + j * 16 + col) < n;
#pragma unroll
        for (int a = 0; a < 2; a++)
#pragma unroll
          for (int r = 0; r < 4; r++)
            s[a][j][r] = valid ? __expf(s[a][j][r] * 0.125f) : 0.f;
      }
      // ---- P: C-layout -> A-layout via per-wave LDS (swizzled scalar writes) ----
#pragma unroll
      for (int a = 0; a < 2; a++)
#pragma unroll
        for (int r = 0; r < 4; r++) {
          int R = a * 16 + quad * 4 + r;
#pragma unroll
          for (int j = 0; j < 4; j++) {
            int chunk = j * 2 + (col >> 3);
            Plds[wv][R * 64 + ((chunk ^ (R & 7)) * 8) + (col & 7)] = f2bf(s[a][j][r]);
          }
        }
      __builtin_amdgcn_fence(__ATOMIC_ACQ_REL, "workgroup");
      bf16x8 pf[2][2];
#pragma unroll
      for (int a = 0; a < 2; a++) {
        int R = a * 16 + col;
        pf[a][0] = *(const bf16x8*)&Plds[wv][R * 64 + ((quad ^ (col & 7)) * 8)];
        pf[a][1] = *(const bf16x8*)&Plds[wv][R * 64 + (((4 + quad) ^ (col & 7)) * 8)];
      }
      // ---- O += P V ; l += P * 1 ----
#pragma unroll
      for (int dt = 0; dt < 4; dt++) {
        int R = dt * 16 + col;
        int gR = ((R >> 4) << 1) ^ (R & 7);
        bf16x8 vf0 = *(const bf16x8*)&Vbuf[cur][R * 64 + ((quad ^ gR) * 8)];
        bf16x8 vf1 = *(const bf16x8*)&Vbuf[cur][R * 64 + (((quad + 4) ^ gR) * 8)];
        oa[0][dt] = __builtin_amdgcn_mfma_f32_16x16x32_bf16(pf[0][0], vf0, oa[0][dt], 0, 0, 0);
        oa[0][dt] = __builtin_amdgcn_mfma_f32_16x16x32_bf16(pf[0][1], vf1, oa[0][dt], 0, 0, 0);
        oa[1][dt] = __builtin_amdgcn_mfma_f32_16x16x32_bf16(pf[1][0], vf0, oa[1][dt], 0, 0, 0);
        oa[1][dt] = __builtin_amdgcn_mfma_f32_16x16x32_bf16(pf[1][1], vf1, oa[1][dt], 0, 0, 0);
      }
      lacc[0] = __builtin_amdgcn_mfma_f32_16x16x32_bf16(pf[0][0], onesv, lacc[0], 0, 0, 0);
      lacc[0] = __builtin_amdgcn_mfma_f32_16x16x32_bf16(pf[0][1], onesv, lacc[0], 0, 0, 0);
      lacc[1] = __builtin_amdgcn_mfma_f32_16x16x32_bf16(pf[1][0], onesv, lacc[1], 0, 0, 0);
      lacc[1] = __builtin_amdgcn_mfma_f32_16x16x32_bf16(pf[1][1], onesv, lacc[1], 0, 0, 0);
    }
    if (t + 1 < ntiles) writelds(1 - cur);
    __syncthreads();
  }

  if (active) {
#pragma unroll
    for (int a = 0; a < 2; a++)
#pragma unroll
      for (int r = 0; r < 4; r++) {
        int q = q0 + a * 16 + quad * 4 + r;
        if (q < n) {
          float inv = 1.0f / lacc[a][r];
          unsigned short* op = obuf + (size_t)(st + q) * DIM + h * 64 + col;
          op[0]  = f2bf(oa[a][0][r] * inv);
          op[16] = f2bf(oa[a][1][r] * inv);
          op[32] = f2bf(oa[a][2][r] * inv);
          op[48] = f2bf(oa[a][3][r] * inv);
        }
      }
  }
}

extern "C" void kernel_launch(void* const* d_in, const int* in_sizes, int n_in,
                              void* d_out, int out_size, void* d_ws, size_t ws_size,
                              hipStream_t stream) {
  const float* z     = (const float*)d_in[0];
  const int*   src   = (const int*)d_in[1];
  const float* gamma = (const float*)d_in[2];
  const float* beta  = (const float*)d_in[3];
  const float* Wq    = (const float*)d_in[4];
  const float* Wk    = (const float*)d_in[5];
  const float* Wv    = (const float*)d_in[6];
  const float* Wo    = (const float*)d_in[7];
  const float* bo    = (const float*)d_in[8];
  int ntot = in_sizes[0] / DIN;
  float* out = (float*)d_out;

  char* ws = (char*)d_ws;
  size_t off = 0;
  unsigned short* zn    = (unsigned short*)(ws + off); off += (size_t)ntot * DIN * 2;
  unsigned short* qkvp  = (unsigned short*)(ws + off); off += (size_t)NPTOT * 1536 * 2;
  unsigned short* obuf  = (unsigned short*)(ws + off); off += (size_t)ntot * DIM * 2;
  unsigned short* WtQKV = (unsigned short*)(ws + off); off += (size_t)1536 * DIN * 2;
  unsigned short* WtO   = (unsigned short*)(ws + off); off += (size_t)DIM * DIN * 2;
  int* starts           = (int*)(ws + off);            off += 64 * 4;
  int* dstrow           = (int*)(ws + off);

  int nln = ntot >> 2;
  int nmap = (ntot + 255) >> 8;
  prep_kernel<<<nln + nmap + 1024, 256, 0, stream>>>(z, gamma, beta, src, Wq, Wk, Wv, Wo,
                                                     zn, starts, dstrow, WtQKV, WtO, ntot);

  // qkvp[g*512+pos][0..1536) = zn @ [Wq|Wk|Wv] (rows scattered to padded slots)
  // hybrid 8-phase: mbig 256-row tiles (dispatched first) + 12 half (128-row) tail tiles
  // -> 324 jobs on 256 CUs, makespan ~1.5T instead of 2T for the uniform 288-grid.
  int mbig = (ntot - 1536) / 256;          // 42 for ntot=12288
  int njobs = mbig * 6 + 72;               // 324
  gemm_qkv_8ph<<<njobs, 512, 0, stream>>>(zn, WtQKV, dstrow, qkvp, mbig);

  // flash attention: grid (graphs, heads, 128-query tiles); V transposed in-LDS
  fattn_kernel<<<dim3(NB, NHEADS, 4), 256, 0, stream>>>(qkvp, starts, obuf);

  // out = obuf @ Wo + bo -> fp32
  gemm_staged<512, true, true, false>
      <<<dim3(ntot / 128, 4), 256, 0, stream>>>(obuf, WtO, bo, nullptr, nullptr, out);
}